// Round 5
// baseline (949.304 us; speedup 1.0000x reference)
//
#include <hip/hip_runtime.h>
#include <hip/hip_bf16.h>
#include <math.h>

#define NPTS 4096
#define CO   256
#define CI   128
#define BB   4
#define DQ   64
#define LL   4
#define PST  136   // Ps row stride in shorts (272B = 68 words; 16B-aligned rows, ~2-way max)

typedef __attribute__((ext_vector_type(8))) short bf16x8;
typedef __attribute__((ext_vector_type(4))) float f32x4;

#define MFMA16(a,b,c) __builtin_amdgcn_mfma_f32_16x16x32_bf16((a),(b),(c),0,0,0)

__device__ __forceinline__ short fb(float x) {
  __hip_bfloat16 h = __float2bfloat16(x);
  return __builtin_bit_cast(short, h);
}
__device__ __forceinline__ float bf(short s) {
  unsigned u = ((unsigned)(unsigned short)s) << 16;
  return __builtin_bit_cast(float, u);
}

// ---------------------------------------------------------------------------
// generic fp32 -> bf16 convert, 8 elements/thread (counts are multiples of 8)
__global__ __launch_bounds__(256) void cvtw_k(
    const float* __restrict__ S, short* __restrict__ D, int n8)
{
  const int i = blockIdx.x * 256 + threadIdx.x;
  if (i < n8) {
    const float4 a = ((const float4*)S)[i * 2];
    const float4 b = ((const float4*)S)[i * 2 + 1];
    bf16x8 r;
    r[0] = fb(a.x); r[1] = fb(a.y); r[2] = fb(a.z); r[3] = fb(a.w);
    r[4] = fb(b.x); r[5] = fb(b.y); r[6] = fb(b.z); r[7] = fb(b.w);
    ((bf16x8*)D)[i] = r;
  }
}

// ---------------------------------------------------------------------------
// fp32 [b][C][N] -> bf16 [b][N][C] transpose-convert (stem input only)
__global__ __launch_bounds__(256) void tcvt_k(
    const float* __restrict__ X, long xbs, int C, short* __restrict__ XT)
{
  const int n0 = blockIdx.x * 64, c0 = blockIdx.y * 64, b = blockIdx.z;
  const int t = threadIdx.x, tl = t & 63, tg = t >> 6;
  __shared__ float xs[64][65];
#pragma unroll
  for (int r = 0; r < 16; ++r) {
    const int cc = tg * 16 + r;
    xs[cc][tl] = X[(long)b * xbs + (long)(c0 + cc) * NPTS + n0 + tl];
  }
  __syncthreads();
#pragma unroll
  for (int r = 0; r < 16; ++r) {
    const int nn = tg * 16 + r;
    XT[((long)b * NPTS + n0 + nn) * C + c0 + tl] = fb(xs[tl][nn]);
  }
}

// ---------------------------------------------------------------------------
// conv_a: Y[b][d][n] = sum_c Wb[d][c] * XT[b][n][c] (+bias), bf16 weights.
// n-tile 128, d-tile 64. OMODE 0: fp32 [d][N]; 1: bf16 n-blocked [n>>7][d][128]
template<int OMODE, bool BIAS>
__global__ __launch_bounds__(256) void conv_a(
    const short* __restrict__ XT, int C,
    const short* __restrict__ Wb, const float* __restrict__ bias,
    void* __restrict__ Yv, long ybs)
{
  const int n0 = blockIdx.x * 128, d0 = blockIdx.y * 64, b = blockIdx.z;
  const int tid = threadIdx.x, w = tid >> 6, l = tid & 63, lg = l >> 4, lr = l & 15;
  const short* xb = XT + (long)b * NPTS * C;
  f32x4 acc[8];
#pragma unroll
  for (int i = 0; i < 8; ++i) acc[i] = (f32x4){0.f, 0.f, 0.f, 0.f};
  const int dr = d0 + w * 16 + lr;
  for (int kc = 0; kc < C; kc += 32) {
    const bf16x8 af = *(const bf16x8*)&Wb[(long)dr * C + kc + lg * 8];
#pragma unroll
    for (int ni = 0; ni < 8; ++ni) {
      const bf16x8 bx = *(const bf16x8*)&xb[(long)(n0 + ni * 16 + lr) * C + kc + lg * 8];
      acc[ni] = MFMA16(af, bx, acc[ni]);
    }
  }
  float bv[4] = {0.f, 0.f, 0.f, 0.f};
  if (BIAS) {
    const float4 b4 = *(const float4*)&bias[d0 + w * 16 + lg * 4];
    bv[0] = b4.x; bv[1] = b4.y; bv[2] = b4.z; bv[3] = b4.w;
  }
  const int db = d0 + w * 16 + lg * 4;
#pragma unroll
  for (int ni = 0; ni < 8; ++ni) {
    const int n = n0 + ni * 16 + lr;
#pragma unroll
    for (int j = 0; j < 4; ++j) {
      const float o = acc[ni][j] + bv[j];
      if constexpr (OMODE == 0) {
        ((float*)Yv)[(long)b * ybs + (long)(db + j) * NPTS + n] = o;
      } else {
        ((short*)Yv)[(long)b * ybs + ((long)(n0 >> 7) * CO + db + j) * 128 + (n & 127)] = fb(o);
      }
    }
  }
}

// ---------------------------------------------------------------------------
// conv_b: KT[b][n][d] = sum_c XT[b][n][c] * Wb[d][c], bf16 weights, Dtot=64.
__global__ __launch_bounds__(256) void conv_b(
    const short* __restrict__ XT, const short* __restrict__ Wb,
    short* __restrict__ KTo)
{
  const int n0 = blockIdx.x * 64, b = blockIdx.y;
  const int tid = threadIdx.x, w = tid >> 6, l = tid & 63, lg = l >> 4, lr = l & 15;
  const short* xb = XT + (long)b * NPTS * CO;
  f32x4 acc[4];
#pragma unroll
  for (int i = 0; i < 4; ++i) acc[i] = (f32x4){0.f, 0.f, 0.f, 0.f};
  const long nr = n0 + w * 16 + lr;
  for (int kc = 0; kc < CO; kc += 32) {
    const bf16x8 af = *(const bf16x8*)&xb[nr * CO + kc + lg * 8];
#pragma unroll
    for (int di = 0; di < 4; ++di) {
      const bf16x8 wf = *(const bf16x8*)&Wb[(long)(di * 16 + lr) * CO + kc + lg * 8];
      acc[di] = MFMA16(af, wf, acc[di]);
    }
  }
  short* Ko = KTo + (long)b * NPTS * DQ;
  const int nb = n0 + w * 16 + lg * 4;
#pragma unroll
  for (int j = 0; j < 4; ++j) {
#pragma unroll
    for (int di = 0; di < 4; ++di)
      Ko[(long)(nb + j) * DQ + di * 16 + lr] = fb(acc[di][j]);
  }
}

// ---------------------------------------------------------------------------
// BN stats per channel over (B, N), vectorized
__global__ __launch_bounds__(256) void bnstats_k(
    const float* __restrict__ X, long xbs,
    float* __restrict__ mean, float* __restrict__ rstd)
{
  const int c = blockIdx.x, t = threadIdx.x;
  float s = 0.f, s2 = 0.f;
  for (int b = 0; b < BB; ++b) {
    const float4* p = (const float4*)(X + (long)b * xbs + (long)c * NPTS);
    for (int n = t; n < NPTS / 4; n += 256) {
      const float4 v = p[n];
      s  += v.x + v.y + v.z + v.w;
      s2 += v.x * v.x + v.y * v.y + v.z * v.z + v.w * v.w;
    }
  }
#pragma unroll
  for (int o = 32; o > 0; o >>= 1) { s += __shfl_down(s, o); s2 += __shfl_down(s2, o); }
  __shared__ float a1[4], a2[4];
  if ((t & 63) == 0) { a1[t >> 6] = s; a2[t >> 6] = s2; }
  __syncthreads();
  if (t == 0) {
    const float S  = a1[0] + a1[1] + a1[2] + a1[3];
    const float S2 = a2[0] + a2[1] + a2[2] + a2[3];
    const float m  = S / (float)(BB * NPTS);
    const float v  = S2 / (float)(BB * NPTS) - m * m;
    mean[c] = m;
    rstd[c] = rsqrtf(v + 1e-5f);
  }
}

// ---------------------------------------------------------------------------
// BN normalize + affine + ReLU, optionally writing fp32 [c][n] (in-place ok)
// and/or bf16 transpose [n][CO]
template<bool WF32, bool WBF>
__global__ __launch_bounds__(256) void bnrelu_t(
    const float* __restrict__ X, long xbs,
    const float* __restrict__ mean, const float* __restrict__ rstd,
    const float* __restrict__ g, const float* __restrict__ be,
    float* __restrict__ Yf, long ybs, short* __restrict__ XT)
{
  const int n0 = blockIdx.x * 64, c0 = blockIdx.y * 64, b = blockIdx.z;
  const int t = threadIdx.x, tl = t & 63, tg = t >> 6;
  __shared__ float xs[64][65];
#pragma unroll
  for (int r = 0; r < 16; ++r) {
    const int cc = tg * 16 + r, c = c0 + cc;
    float v = X[(long)b * xbs + (long)c * NPTS + n0 + tl];
    v = fmaxf((v - mean[c]) * rstd[c] * g[c] + be[c], 0.f);
    if (WF32) Yf[(long)b * ybs + (long)c * NPTS + n0 + tl] = v;
    xs[cc][tl] = v;
  }
  __syncthreads();
  if (WBF) {
#pragma unroll
    for (int r = 0; r < 16; ++r) {
      const int nn = tg * 16 + r;
      XT[((long)b * NPTS + n0 + nn) * CO + c0 + tl] = fb(xs[tl][nn]);
    }
  }
}

// ---------------------------------------------------------------------------
// pass1: per-row softmax stats of S = K^T K over an m-chunk (MFMA).
// 4-way m-parallel online stats (16 independent chains) + single-exp update.
__global__ __launch_bounds__(256) void rowstats_mfma(
    const short* __restrict__ KT, float* __restrict__ pmax, float* __restrict__ psum)
{
  const int bid = blockIdx.x;
  const int b = (bid >> 1) & 3;
  const int idx = (bid >> 3) * 2 + (bid & 1);   // 0..255
  const int n0 = (idx & 63) * 64;
  const int chunk = idx >> 6;
  const int tid = threadIdx.x, w = tid >> 6, l = tid & 63, lg = l >> 4, lr = l & 15;
  const short* Kb = KT + (long)b * NPTS * DQ;
  const int nr = n0 + w * 16 + lr;
  const bf16x8 a0 = *(const bf16x8*)&Kb[(long)nr * DQ + lg * 8];
  const bf16x8 a1 = *(const bf16x8*)&Kb[(long)nr * DQ + 32 + lg * 8];

  float mx[4][4], sm[4][4];
#pragma unroll
  for (int p = 0; p < 4; ++p)
#pragma unroll
    for (int j = 0; j < 4; ++j) { mx[p][j] = -INFINITY; sm[p][j] = 0.f; }

  const int mc = chunk * (NPTS / 4);
  for (int m0 = mc; m0 < mc + NPTS / 4; m0 += 64) {
#pragma unroll
    for (int p = 0; p < 4; ++p) {
      const bf16x8 b0 = *(const bf16x8*)&Kb[(long)(m0 + p * 16 + lr) * DQ + lg * 8];
      const bf16x8 b1 = *(const bf16x8*)&Kb[(long)(m0 + p * 16 + lr) * DQ + 32 + lg * 8];
      f32x4 s = {0.f, 0.f, 0.f, 0.f};
      s = MFMA16(a0, b0, s);
      s = MFMA16(a1, b1, s);
#pragma unroll
      for (int j = 0; j < 4; ++j) {
        const float d = s[j] - mx[p][j];
        const float e = __expf(-fabsf(d));
        const bool gt = d > 0.f;
        sm[p][j] = gt ? fmaf(sm[p][j], e, 1.f) : (sm[p][j] + e);
        mx[p][j] = gt ? s[j] : mx[p][j];
      }
    }
  }
  // merge the 4 m-parallel chains
#pragma unroll
  for (int p = 1; p < 4; ++p)
#pragma unroll
    for (int j = 0; j < 4; ++j) {
      const float m2 = fmaxf(mx[0][j], mx[p][j]);
      sm[0][j] = sm[0][j] * __expf(mx[0][j] - m2) + sm[p][j] * __expf(mx[p][j] - m2);
      mx[0][j] = m2;
    }

  float mx0 = mx[0][0], mx1 = mx[0][1], mx2 = mx[0][2], mx3 = mx[0][3];
  float sm0 = sm[0][0], sm1 = sm[0][1], sm2 = sm[0][2], sm3 = sm[0][3];
#define MRG(MX, SM, OFF) { const float om_ = __shfl_xor(MX, OFF); \
  const float os_ = __shfl_xor(SM, OFF); \
  const float m2_ = fmaxf(MX, om_); \
  SM = SM * __expf(MX - m2_) + os_ * __expf(om_ - m2_); MX = m2_; }
#pragma unroll
  for (int off = 1; off < 16; off <<= 1) {
    MRG(mx0, sm0, off); MRG(mx1, sm1, off);
    MRG(mx2, sm2, off); MRG(mx3, sm3, off);
  }
  if (lr == 0) {
    const long base = ((long)chunk * BB + b) * NPTS + n0 + w * 16 + lg * 4;
    pmax[base + 0] = mx0; pmax[base + 1] = mx1; pmax[base + 2] = mx2; pmax[base + 3] = mx3;
    psum[base + 0] = sm0; psum[base + 1] = sm1; psum[base + 2] = sm2; psum[base + 3] = sm3;
  }
}

__global__ __launch_bounds__(256) void combine_k(
    const float* __restrict__ pmax, const float* __restrict__ psum,
    float* __restrict__ rmax, float* __restrict__ rinv)
{
  const long i = (long)blockIdx.x * 256 + threadIdx.x;
  const long st = (long)BB * NPTS;
  float m = pmax[i];
  m = fmaxf(m, pmax[st + i]); m = fmaxf(m, pmax[2 * st + i]); m = fmaxf(m, pmax[3 * st + i]);
  const float s = psum[i] * __expf(pmax[i] - m)
                + psum[st + i] * __expf(pmax[st + i] - m)
                + psum[2 * st + i] * __expf(pmax[2 * st + i] - m)
                + psum[3 * st + i] * __expf(pmax[3 * st + i] - m);
  rmax[i] = m;
  rinv[i] = 1.f / s;
}

// ---------------------------------------------------------------------------
// pass2 v4: software-pipelined — S/exp for iter i+1 overlaps PV MFMAs of
// iter i across the double-buffered Ps. One lgkm-only barrier per iter.
// m-tile 64, n-step 128, XCD-swizzled. Epilogue: colsum renorm + off = x - nf.
__global__ __launch_bounds__(512) void pass2_mfma(
    const short* __restrict__ KT, const short* __restrict__ Vblk,
    const float* __restrict__ rmax, const float* __restrict__ rinv,
    short* __restrict__ XO)
{
  const int bid = blockIdx.x;
  const int b  = (bid >> 1) & 3;
  const int m0 = ((bid >> 3) * 2 + (bid & 1)) * 64;   // 0..4032
  const int tid = threadIdx.x;
  const int w = tid >> 6, l = tid & 63, lg = l >> 4, lr = l & 15;
  const int NT = NPTS / 128;   // 32

  const short* Kb = KT + (long)b * NPTS * DQ;
  const short* Vb = Vblk + (long)b * CO * NPTS;
  const float* rmb = rmax + (long)b * NPTS;
  const float* rib = rinv + (long)b * NPTS;

  __shared__ short Ps[2][64][PST];
  __shared__ float cspart[8][64];
  __shared__ float csum[64];

  // block-fixed K m-frags: 4 m-subtiles x 2 k-chunks
  bf16x8 bK[4][2];
#pragma unroll
  for (int ms = 0; ms < 4; ++ms) {
    bK[ms][0] = *(const bf16x8*)&Kb[(long)(m0 + ms * 16 + lr) * DQ + lg * 8];
    bK[ms][1] = *(const bf16x8*)&Kb[(long)(m0 + ms * 16 + lr) * DQ + 32 + lg * 8];
  }

  f32x4 acc[4][2];   // [m-sub][c-sub]
#pragma unroll
  for (int i = 0; i < 4; ++i) {
    acc[i][0] = (f32x4){0.f, 0.f, 0.f, 0.f};
    acc[i][1] = (f32x4){0.f, 0.f, 0.f, 0.f};
  }
  float cs[4] = {0.f, 0.f, 0.f, 0.f};
  const int c0 = w * 32;   // PV role: c-range
  const int nb = w * 16;   // S role: n-frag within 128-step

  bf16x8 a0, a1;           // K n-frags for the "next" S block
  float4 rm4, ri4;

  // S block: compute S for n-rows [n_base+nb, +16), softmax to P, write Ps[dbuf]
  auto sblk = [&](int dbuf) {
    f32x4 s[4];
#pragma unroll
    for (int ms = 0; ms < 4; ++ms) {
      s[ms] = (f32x4){0.f, 0.f, 0.f, 0.f};
      s[ms] = MFMA16(a0, bK[ms][0], s[ms]);
      s[ms] = MFMA16(a1, bK[ms][1], s[ms]);
    }
#pragma unroll
    for (int ms = 0; ms < 4; ++ms) {
      const float p0 = __expf(s[ms][0] - rm4.x) * ri4.x;
      const float p1 = __expf(s[ms][1] - rm4.y) * ri4.y;
      const float p2 = __expf(s[ms][2] - rm4.z) * ri4.z;
      const float p3 = __expf(s[ms][3] - rm4.w) * ri4.w;
      cs[ms] += p0 + p1 + p2 + p3;
      const unsigned u0 = ((unsigned)(unsigned short)fb(p1) << 16) | (unsigned short)fb(p0);
      const unsigned u1 = ((unsigned)(unsigned short)fb(p3) << 16) | (unsigned short)fb(p2);
      *(uint2*)&Ps[dbuf][ms * 16 + lr][nb + lg * 4] = make_uint2(u0, u1);
    }
  };

  // prologue: S_0 -> Ps[0], then prefetch iter-1 operands
  a0  = *(const bf16x8*)&Kb[(long)(nb + lr) * DQ + lg * 8];
  a1  = *(const bf16x8*)&Kb[(long)(nb + lr) * DQ + 32 + lg * 8];
  rm4 = *(const float4*)&rmb[nb + lg * 4];
  ri4 = *(const float4*)&rib[nb + lg * 4];
  sblk(0);
  a0  = *(const bf16x8*)&Kb[(long)(128 + nb + lr) * DQ + lg * 8];
  a1  = *(const bf16x8*)&Kb[(long)(128 + nb + lr) * DQ + 32 + lg * 8];
  rm4 = *(const float4*)&rmb[128 + nb + lg * 4];
  ri4 = *(const float4*)&rib[128 + nb + lg * 4];

  for (int i = 0; i < NT; ++i) {
    const int n0 = i * 128;
    // make Ps[i&1] visible; prior-iter LDS reads done; V loads NOT drained
    asm volatile("s_waitcnt lgkmcnt(0)" ::: "memory");
    __builtin_amdgcn_s_barrier();

    // issue V loads for iter i (contiguous 8KB/wave region)
    const short* vt = Vb + (long)(n0 >> 7) * CO * 128;
    bf16x8 vf[4][2];
#pragma unroll
    for (int kc = 0; kc < 4; ++kc) {
      vf[kc][0] = *(const bf16x8*)&vt[(long)(c0 + lr) * 128 + kc * 32 + lg * 8];
      vf[kc][1] = *(const bf16x8*)&vt[(long)(c0 + 16 + lr) * 128 + kc * 32 + lg * 8];
    }
    // issue P reads for iter i
    bf16x8 pa[4][4];   // [ms][kc]
#pragma unroll
    for (int kc = 0; kc < 4; ++kc)
#pragma unroll
      for (int ms = 0; ms < 4; ++ms)
        pa[ms][kc] = *(const bf16x8*)&Ps[i & 1][ms * 16 + lr][kc * 32 + lg * 8];

    // overlap: compute S_{i+1} into the other buffer while PV of iter i runs
    if (i + 1 < NT) {
      sblk((i + 1) & 1);
      if (i + 2 < NT) {
        a0  = *(const bf16x8*)&Kb[(long)((i + 2) * 128 + nb + lr) * DQ + lg * 8];
        a1  = *(const bf16x8*)&Kb[(long)((i + 2) * 128 + nb + lr) * DQ + 32 + lg * 8];
        rm4 = *(const float4*)&rmb[(i + 2) * 128 + nb + lg * 4];
        ri4 = *(const float4*)&rib[(i + 2) * 128 + nb + lg * 4];
      }
    }

    // PV MFMAs for iter i
#pragma unroll
    for (int kc = 0; kc < 4; ++kc)
#pragma unroll
      for (int ms = 0; ms < 4; ++ms) {
        acc[ms][0] = MFMA16(pa[ms][kc], vf[kc][0], acc[ms][0]);
        acc[ms][1] = MFMA16(pa[ms][kc], vf[kc][1], acc[ms][1]);
      }
  }

  // colsum: lane (lg,lr) of wave w holds partials for column ms*16+lr
  __syncthreads();
#pragma unroll
  for (int ms = 0; ms < 4; ++ms) {
    float csv = cs[ms];
    csv += __shfl_xor(csv, 16); csv += __shfl_xor(csv, 32);
    if (lg == 0) cspart[w][ms * 16 + lr] = csv;
  }
  __syncthreads();
  if (tid < 64) {
    float s = 0.f;
#pragma unroll
    for (int ww = 0; ww < 8; ++ww) s += cspart[ww][tid];
    csum[tid] = s;
  }
  __syncthreads();

  short* XOb = XO + (long)b * NPTS * CO;
#pragma unroll
  for (int ms = 0; ms < 4; ++ms) {
#pragma unroll
    for (int j = 0; j < 4; ++j) {
      const int m = m0 + ms * 16 + lg * 4 + j;
      const float inv = 1.f / (1e-9f + csum[ms * 16 + lg * 4 + j]);
      const long i0 = (long)m * CO + c0 + lr;
      const long i1 = (long)m * CO + c0 + 16 + lr;
      XOb[i0] = fb(bf(XOb[i0]) - acc[ms][0][j] * inv);
      XOb[i1] = fb(bf(XOb[i1]) - acc[ms][1][j] * inv);
    }
  }
}

// ---------------------------------------------------------------------------
extern "C" void kernel_launch(void* const* d_in, const int* in_sizes, int n_in,
                              void* d_out, int out_size, void* d_ws, size_t ws_size,
                              hipStream_t stream)
{
  const float* feat = (const float*)d_in[0];
  const float* w1   = (const float*)d_in[1];
  const float* g1   = (const float*)d_in[2];
  const float* b1   = (const float*)d_in[3];
  const float* w2   = (const float*)d_in[4];
  const float* g2   = (const float*)d_in[5];
  const float* b2   = (const float*)d_in[6];
  const float* qkw  = (const float*)d_in[7];
  const float* vw   = (const float*)d_in[8];
  const float* vb   = (const float*)d_in[9];
  const float* tw   = (const float*)d_in[10];
  const float* tb   = (const float*)d_in[11];
  const float* bng  = (const float*)d_in[12];
  const float* bnb  = (const float*)d_in[13];

  float* out = (float*)d_out;

  // workspace (~20 MB)
  short* xt    = (short*)d_ws;                        // [B][N][CO] bf16 (x^T, then off^T)
  short* KTb   = xt + (long)BB * NPTS * CO;           // [B][N][DQ]
  short* Vblk  = KTb + (long)BB * NPTS * DQ;          // [B][N/128][CO][128]
  short* wb1   = Vblk + (long)BB * CO * NPTS;         // CO*CI
  short* wb2   = wb1 + (long)CO * CI;                 // CO*CO
  short* wqk   = wb2 + (long)CO * CO;                 // L*DQ*CO
  short* wv    = wqk + (long)LL * DQ * CO;            // L*CO*CO
  short* wt    = wv + (long)LL * CO * CO;             // L*CO*CO
  float* pmaxb = (float*)(wt + (long)LL * CO * CO);   // [4][B][N]
  float* psumb = pmaxb + (long)4 * BB * NPTS;
  float* rmaxb = psumb + (long)4 * BB * NPTS;         // [B][N]
  float* rinvb = rmaxb + (long)BB * NPTS;
  float* meanb = rinvb + (long)BB * NPTS;             // [CO]
  float* rstdb = meanb + CO;

  const long OBS = (long)LL * CO * NPTS;
  float* h1 = out + (long)2 * CO * NPTS;  // stem scratch in slice-2 region
  float* x0 = out + (long)1 * CO * NPTS;  // stem scratch in slice-1 region

  const dim3 blk(256);

  // ---- weight pre-convert (fp32 -> bf16, once per call) ----
  cvtw_k<<<dim3((CO * CI / 8 + 255) / 256), blk, 0, stream>>>(w1, wb1, CO * CI / 8);
  cvtw_k<<<dim3((CO * CO / 8 + 255) / 256), blk, 0, stream>>>(w2, wb2, CO * CO / 8);
  cvtw_k<<<dim3((LL * DQ * CO / 8 + 255) / 256), blk, 0, stream>>>(qkw, wqk, LL * DQ * CO / 8);
  cvtw_k<<<dim3((LL * CO * CO / 8 + 255) / 256), blk, 0, stream>>>(vw, wv, LL * CO * CO / 8);
  cvtw_k<<<dim3((LL * CO * CO / 8 + 255) / 256), blk, 0, stream>>>(tw, wt, LL * CO * CO / 8);

  // ---- stem ----
  tcvt_k<<<dim3(64, 2, BB), blk, 0, stream>>>(feat, (long)CI * NPTS, CI, xt);
  conv_a<0, false><<<dim3(32, 4, BB), blk, 0, stream>>>(xt, CI, wb1, nullptr, h1, OBS);
  bnstats_k<<<dim3(CO), blk, 0, stream>>>(h1, OBS, meanb, rstdb);
  bnrelu_t<false, true><<<dim3(64, 4, BB), blk, 0, stream>>>(
      h1, OBS, meanb, rstdb, g1, b1, nullptr, 0, xt);
  conv_a<0, false><<<dim3(32, 4, BB), blk, 0, stream>>>(xt, CO, wb2, nullptr, x0, OBS);
  bnstats_k<<<dim3(CO), blk, 0, stream>>>(x0, OBS, meanb, rstdb);
  bnrelu_t<false, true><<<dim3(64, 4, BB), blk, 0, stream>>>(
      x0, OBS, meanb, rstdb, g2, b2, nullptr, 0, xt);

  // ---- stacked offset attention ----
  for (int lyr = 0; lyr < LL; ++lyr) {
    float* nft = out + (long)lyr * CO * NPTS;
    conv_b<<<dim3(64, BB), blk, 0, stream>>>(xt, wqk + (long)lyr * DQ * CO, KTb);
    conv_a<1, true><<<dim3(32, 4, BB), blk, 0, stream>>>(
        xt, CO, wv + (long)lyr * CO * CO, vb + (long)lyr * CO, Vblk, (long)CO * NPTS);
    rowstats_mfma<<<dim3(1024), blk, 0, stream>>>(KTb, pmaxb, psumb);
    combine_k<<<dim3(BB * NPTS / 256), blk, 0, stream>>>(pmaxb, psumb, rmaxb, rinvb);
    pass2_mfma<<<dim3(256), dim3(512), 0, stream>>>(KTb, Vblk, rmaxb, rinvb, xt);
    conv_a<0, true><<<dim3(32, 4, BB), blk, 0, stream>>>(
        xt, CO, wt + (long)lyr * CO * CO, tb + (long)lyr * CO, nft, OBS);
    bnstats_k<<<dim3(CO), blk, 0, stream>>>(nft, OBS, meanb, rstdb);
    if (lyr < LL - 1) {
      bnrelu_t<true, true><<<dim3(64, 4, BB), blk, 0, stream>>>(
          nft, OBS, meanb, rstdb, bng + (long)lyr * CO, bnb + (long)lyr * CO, nft, OBS, xt);
    } else {
      bnrelu_t<true, false><<<dim3(64, 4, BB), blk, 0, stream>>>(
          nft, OBS, meanb, rstdb, bng + (long)lyr * CO, bnb + (long)lyr * CO, nft, OBS, nullptr);
    }
  }
}